// Round 3
// baseline (1813.188 us; speedup 1.0000x reference)
//
#include <hip/hip_runtime.h>
#include <math.h>

#define NN 50000
#define NE 800000
#define NEG_SLOPE 0.2f
#define LN_EPS 1e-5f

typedef unsigned short ushort_t;
typedef unsigned int uint_t;

__device__ __forceinline__ float bf2f(ushort_t u) {
    return __uint_as_float(((uint_t)u) << 16);
}
__device__ __forceinline__ ushort_t f2bf(float f) {
    uint_t b = __float_as_uint(f);
    uint_t r = (b + 0x7fffu + ((b >> 16) & 1u)) >> 16;
    return (ushort_t)r;
}
// generic float-input load: isbf ? bf16[i] : f32[i]
__device__ __forceinline__ float ldx(const void* p, size_t i, int isbf) {
    return isbf ? bf2f(((const ushort_t*)p)[i]) : ((const float*)p)[i];
}
// order-preserving float -> uint key (for atomicMax segment-max)
__device__ __forceinline__ uint_t fkey(float f) {
    uint_t b = __float_as_uint(f);
    return (b & 0x80000000u) ? ~b : (b | 0x80000000u);
}
__device__ __forceinline__ float fdec(uint_t k) {
    uint_t b = (k & 0x80000000u) ? (k & 0x7FFFFFFFu) : ~k;
    return __uint_as_float(b);
}
__device__ __forceinline__ int clampN(int v) {
    return v < 0 ? 0 : (v >= NN ? NN - 1 : v);
}
// edge-index loads, robust to int64 storage (low word holds value: 0<=idx<2^31)
__device__ __forceinline__ int ld_src(const int* ei, int e, int f64) {
    return clampN(f64 ? ei[2 * e] : ei[e]);
}
__device__ __forceinline__ int ld_dst(const int* ei, int e, int f64) {
    return clampN(f64 ? ei[2 * NE + 2 * e] : ei[NE + e]);
}

// flags[0] = edge_index-is-int64, flags[1] = floats-are-bf16
__global__ void detect_flags(const int* __restrict__ ei, const void* __restrict__ hptr,
                             int* __restrict__ flags) {
    if (threadIdx.x != 0) return;
    flags[0] = (ei[1] == 0 && ei[3] == 0 && ei[5] == 0 && ei[7] == 0) ? 1 : 0;
    // bf16 storage: every even u16 of h is a sane bf16 (|v| < 1e4).
    // f32 storage: even u16s are mantissa slices -> uniform exponents; the
    // probability all 256 look sane is 0.55^256 ~ 1e-66.
    const ushort_t* hu = (const ushort_t*)hptr;
    int bf = 1;
    for (int i = 0; i < 512; i += 2) {
        uint_t ex = (hu[i] >> 7) & 0xFFu;  // bf16 exponent field
        if (ex > 0x8Cu) bf = 0;            // |v| >= ~1e4 -> not bf16 data
    }
    flags[1] = bf;
}

// M[l][h][d] = sum_c lin_edge_W[l, h*64+c, d] * att_edge[l, h, c]
__global__ void precompute_M(const void* __restrict__ lin_edge_W,
                             const void* __restrict__ att_edge,
                             float* __restrict__ Mbuf, const int* __restrict__ flags) {
    int isbf = flags[1];
    int tid = threadIdx.x;  // 512 threads: l = tid>>8, h=(tid>>6)&3, c=tid&63
    int l = tid >> 8;
    int hc = tid & 255;
    float ae = ldx(att_edge, l * 256 + hc, isbf);
    size_t base = ((size_t)l * 256 + hc) * 3;
    float p0 = ae * ldx(lin_edge_W, base + 0, isbf);
    float p1 = ae * ldx(lin_edge_W, base + 1, isbf);
    float p2 = ae * ldx(lin_edge_W, base + 2, isbf);
    for (int off = 32; off > 0; off >>= 1) {
        p0 += __shfl_down(p0, off);
        p1 += __shfl_down(p1, off);
        p2 += __shfl_down(p2, off);
    }
    if ((tid & 63) == 0) {
        int h = (tid >> 6) & 3;
        Mbuf[(l * 4 + h) * 3 + 0] = p0;
        Mbuf[(l * 4 + h) * 3 + 1] = p1;
        Mbuf[(l * 4 + h) * 3 + 2] = p2;
    }
}

// Per node: x = z @ W^T (256 outs, stored bf16), a_src/a_dst head reductions,
// init out_acc (=bias), amax (=0 key floor), denom (=0).
__global__ __launch_bounds__(256) void node_linear(
    const float* __restrict__ zin,   // null for layer 0 -> use h input
    const void* __restrict__ h_in,   // N*64
    const void* __restrict__ lin_W,  // L*256*64
    const void* __restrict__ att_src,
    const void* __restrict__ att_dst,
    const void* __restrict__ bias,   // L*64
    ushort_t* __restrict__ xb,       // N*256 bf16
    float* __restrict__ a_src, float* __restrict__ a_dst,
    float* __restrict__ out_acc,     // N*64
    uint_t* __restrict__ amax, float* __restrict__ denom,
    const int* __restrict__ flags, int layer) {
    __shared__ float zsh[64];
    int isbf = flags[1];
    int n = blockIdx.x;
    int tid = threadIdx.x;
    if (tid < 64) {
        zsh[tid] = zin ? zin[(size_t)n * 64 + tid] : ldx(h_in, (size_t)n * 64 + tid, isbf);
    }
    __syncthreads();
    int o = tid;  // output channel 0..255
    size_t wrow = ((size_t)layer * 256 + o) * 64;
    float acc = 0.f;
    if (isbf) {
        const uint_t* wr = (const uint_t*)((const ushort_t*)lin_W + wrow);
#pragma unroll
        for (int i = 0; i < 32; ++i) {
            uint_t p = wr[i];
            acc += zsh[2 * i] * __uint_as_float(p << 16) +
                   zsh[2 * i + 1] * __uint_as_float(p & 0xffff0000u);
        }
    } else {
        const float* wr = (const float*)lin_W + wrow;
#pragma unroll
        for (int i = 0; i < 64; ++i) acc += zsh[i] * wr[i];
    }
    xb[(size_t)n * 256 + o] = f2bf(acc);
    int h = o >> 6;
    float ps = acc * ldx(att_src, layer * 256 + o, isbf);
    float pd = acc * ldx(att_dst, layer * 256 + o, isbf);
    for (int off = 32; off > 0; off >>= 1) {
        ps += __shfl_down(ps, off);
        pd += __shfl_down(pd, off);
    }
    if ((tid & 63) == 0) {
        a_src[n * 4 + h] = ps;
        a_dst[n * 4 + h] = pd;
    }
    if (tid < 64) out_acc[(size_t)n * 64 + tid] = ldx(bias, layer * 64 + tid, isbf);
    if (tid < 4) {
        amax[n * 4 + tid] = 0u;
        denom[n * 4 + tid] = 0.f;
    }
}

// Per edge: alpha = leakyrelu(a_src[src]+a_dst[dst]+edge_attr@M^T); atomicMax segment-max.
__global__ __launch_bounds__(256) void edge_alpha(
    const int* __restrict__ ei, const void* __restrict__ edge_attr,
    const float* __restrict__ a_src, const float* __restrict__ a_dst,
    const float* __restrict__ Mbuf, float* __restrict__ alpha,
    uint_t* __restrict__ amax, const int* __restrict__ flags, int layer) {
    __shared__ float Msh[12];
    if (threadIdx.x < 12) Msh[threadIdx.x] = Mbuf[layer * 12 + threadIdx.x];
    __syncthreads();
    int e = blockIdx.x * 256 + threadIdx.x;
    int f64 = flags[0], isbf = flags[1];
    int src = ld_src(ei, e, f64), dst = ld_dst(ei, e, f64);
    float4 as4 = *(const float4*)(a_src + (size_t)src * 4);
    float4 ad4 = *(const float4*)(a_dst + (size_t)dst * 4);
    float ea0 = ldx(edge_attr, (size_t)e * 3 + 0, isbf);
    float ea1 = ldx(edge_attr, (size_t)e * 3 + 1, isbf);
    float ea2 = ldx(edge_attr, (size_t)e * 3 + 2, isbf);
    float asv[4] = {as4.x, as4.y, as4.z, as4.w};
    float adv[4] = {ad4.x, ad4.y, ad4.z, ad4.w};
    float v[4];
#pragma unroll
    for (int h = 0; h < 4; ++h) {
        float t = asv[h] + adv[h] + ea0 * Msh[h * 3] + ea1 * Msh[h * 3 + 1] + ea2 * Msh[h * 3 + 2];
        t = t > 0.f ? t : NEG_SLOPE * t;
        v[h] = t;
        atomicMax(&amax[(size_t)dst * 4 + h], fkey(t));
    }
    *(float4*)(alpha + (size_t)e * 4) = make_float4(v[0], v[1], v[2], v[3]);
}

// Per edge: ex = exp(alpha - amax[dst]); denom += ex (alpha overwritten with ex).
__global__ __launch_bounds__(256) void edge_exp(
    const int* __restrict__ ei, float* __restrict__ alpha,
    const uint_t* __restrict__ amax, float* __restrict__ denom,
    const int* __restrict__ flags) {
    int e = blockIdx.x * 256 + threadIdx.x;
    int dst = ld_dst(ei, e, flags[0]);
    float4 al = *(const float4*)(alpha + (size_t)e * 4);
    uint4 km = *(const uint4*)(amax + (size_t)dst * 4);
    float e0 = __expf(al.x - fdec(km.x));
    float e1 = __expf(al.y - fdec(km.y));
    float e2 = __expf(al.z - fdec(km.z));
    float e3 = __expf(al.w - fdec(km.w));
    *(float4*)(alpha + (size_t)e * 4) = make_float4(e0, e1, e2, e3);
    atomicAdd(&denom[(size_t)dst * 4 + 0], e0);
    atomicAdd(&denom[(size_t)dst * 4 + 1], e1);
    atomicAdd(&denom[(size_t)dst * 4 + 2], e2);
    atomicAdd(&denom[(size_t)dst * 4 + 3], e3);
}

// Per (edge, channel): out_acc[dst,c] += 0.25 * sum_h w[e,h] * x[src, h*64+c]
__global__ __launch_bounds__(256) void edge_scatter(
    const int* __restrict__ ei, const float* __restrict__ exbuf,
    const float* __restrict__ denom, const ushort_t* __restrict__ xb,
    float* __restrict__ out_acc, const int* __restrict__ flags) {
    uint_t idx = blockIdx.x * 256u + threadIdx.x;
    int e = (int)(idx >> 6);
    int c = (int)(idx & 63u);
    int f64 = flags[0];
    int src = ld_src(ei, e, f64), dst = ld_dst(ei, e, f64);
    float4 ex = *(const float4*)(exbuf + (size_t)e * 4);
    float4 dn = *(const float4*)(denom + (size_t)dst * 4);
    float w0 = ex.x / (dn.x + 1e-16f);
    float w1 = ex.y / (dn.y + 1e-16f);
    float w2 = ex.z / (dn.z + 1e-16f);
    float w3 = ex.w / (dn.w + 1e-16f);
    const ushort_t* xr = xb + (size_t)src * 256;
    float val = 0.25f * (w0 * bf2f(xr[c]) + w1 * bf2f(xr[64 + c]) +
                         w2 * bf2f(xr[128 + c]) + w3 * bf2f(xr[192 + c]));
    atomicAdd(&out_acc[(size_t)dst * 64 + c], val);
}

// One wave per node: LayerNorm over 64 channels + SiLU.
// Not-last layer: writes z in-place into out_acc. Last layer: writes output
// (dtype matches the detected input float dtype).
__global__ __launch_bounds__(256) void node_finish(
    float* __restrict__ out_acc, const void* __restrict__ gamma,
    const void* __restrict__ beta, void* __restrict__ outp,
    const int* __restrict__ flags, int layer, int last) {
    int isbf = flags[1];
    int node = blockIdx.x * 4 + (threadIdx.x >> 6);
    int lane = threadIdx.x & 63;
    size_t idx = (size_t)node * 64 + lane;
    float v = out_acc[idx];
    float s = v;
    for (int off = 1; off < 64; off <<= 1) s += __shfl_xor(s, off);
    float mu = s * (1.f / 64.f);
    float d = v - mu;
    float vv = d * d;
    for (int off = 1; off < 64; off <<= 1) vv += __shfl_xor(vv, off);
    float var = vv * (1.f / 64.f);
    float ln = d * rsqrtf(var + LN_EPS) * ldx(gamma, layer * 64 + lane, isbf) +
               ldx(beta, layer * 64 + lane, isbf);
    float sl = ln / (1.f + __expf(-ln));
    if (last) {
        if (isbf) ((ushort_t*)outp)[idx] = f2bf(sl);
        else      ((float*)outp)[idx] = sl;
    } else {
        out_acc[idx] = sl;  // in-place: z for next layer
    }
}

extern "C" void kernel_launch(void* const* d_in, const int* in_sizes, int n_in,
                              void* d_out, int out_size, void* d_ws, size_t ws_size,
                              hipStream_t stream) {
    // dict order: t[1], h, edge_index, edge_attr, lin_W, lin_edge_W,
    // att_src, att_dst, att_edge, bias, ln_gamma, ln_beta
    int off = (in_sizes[0] == 1) ? 1 : 0;
    const void* h_in  = d_in[off + 0];
    const int*  ei    = (const int*)d_in[off + 1];
    const void* eattr = d_in[off + 2];
    const void* linW  = d_in[off + 3];
    const void* linEW = d_in[off + 4];
    const void* attS  = d_in[off + 5];
    const void* attD  = d_in[off + 6];
    const void* attE  = d_in[off + 7];
    const void* bias  = d_in[off + 8];
    const void* gamma = d_in[off + 9];
    const void* beta  = d_in[off + 10];

    // workspace layout (~54.4 MB total)
    char* w = (char*)d_ws;
    int*    flags  = (int*)w;                             // 2 ints
    float*  Mbuf   = (float*)(w + 64);                    // 24 f32
    float*  a_src  = (float*)(w + 4096);                  // N*4 f32
    float*  a_dst  = a_src + (size_t)NN * 4;
    float*  denom  = a_dst + (size_t)NN * 4;
    uint_t* amax   = (uint_t*)(denom + (size_t)NN * 4);
    float*  outacc = (float*)(amax + (size_t)NN * 4);     // N*64 f32 (doubles as z)
    float*  alpha  = outacc + (size_t)NN * 64;            // E*4 f32
    ushort_t* xb   = (ushort_t*)(alpha + (size_t)NE * 4); // N*256 bf16

    detect_flags<<<1, 64, 0, stream>>>(ei, h_in, flags);
    precompute_M<<<1, 512, 0, stream>>>(linEW, attE, Mbuf, flags);
    for (int l = 0; l < 2; ++l) {
        node_linear<<<NN, 256, 0, stream>>>(l == 0 ? nullptr : outacc, h_in, linW,
                                            attS, attD, bias, xb, a_src, a_dst,
                                            outacc, amax, denom, flags, l);
        edge_alpha<<<NE / 256, 256, 0, stream>>>(ei, eattr, a_src, a_dst, Mbuf,
                                                 alpha, amax, flags, l);
        edge_exp<<<NE / 256, 256, 0, stream>>>(ei, alpha, amax, denom, flags);
        edge_scatter<<<(NE * 64) / 256, 256, 0, stream>>>(ei, alpha, denom, xb,
                                                          outacc, flags);
        node_finish<<<NN / 4, 256, 0, stream>>>(outacc, gamma, beta, d_out,
                                                flags, l, l == 1);
    }
}

// Round 4
// 1001.520 us; speedup vs baseline: 1.8104x; 1.8104x over previous
//
#include <hip/hip_runtime.h>
#include <math.h>

#define NN 50000
#define NE 800000
#define NEG_SLOPE 0.2f
#define LN_EPS 1e-5f
#define MTILE 64

typedef unsigned short ushort_t;
typedef unsigned int uint_t;

__device__ __forceinline__ float bf2f(ushort_t u) {
    return __uint_as_float(((uint_t)u) << 16);
}
__device__ __forceinline__ ushort_t f2bf(float f) {
    uint_t b = __float_as_uint(f);
    uint_t r = (b + 0x7fffu + ((b >> 16) & 1u)) >> 16;
    return (ushort_t)r;
}
// generic float-input load: isbf ? bf16[i] : f32[i]
__device__ __forceinline__ float ldx(const void* p, size_t i, int isbf) {
    return isbf ? bf2f(((const ushort_t*)p)[i]) : ((const float*)p)[i];
}
__device__ __forceinline__ int clampN(int v) {
    return v < 0 ? 0 : (v >= NN ? NN - 1 : v);
}
// edge-index loads, robust to int64 storage (low word holds value)
__device__ __forceinline__ int ld_src(const int* ei, int e, int f64) {
    return clampN(f64 ? ei[2 * e] : ei[e]);
}
__device__ __forceinline__ int ld_dst(const int* ei, int e, int f64) {
    return clampN(f64 ? ei[2 * NE + 2 * e] : ei[NE + e]);
}

// flags[0] = edge_index-is-int64, flags[1] = floats-are-bf16
__global__ void detect_flags(const int* __restrict__ ei, const void* __restrict__ hptr,
                             int* __restrict__ flags) {
    if (threadIdx.x != 0) return;
    flags[0] = (ei[1] == 0 && ei[3] == 0 && ei[5] == 0 && ei[7] == 0) ? 1 : 0;
    const ushort_t* hu = (const ushort_t*)hptr;
    int bf = 1;
    for (int i = 0; i < 512; i += 2) {
        uint_t ex = (hu[i] >> 7) & 0xFFu;
        if (ex > 0x8Cu) bf = 0;  // |v| >= ~1e4 -> not bf16 data
    }
    flags[1] = bf;
}

// M[l][h][d] = sum_c lin_edge_W[l, h*64+c, d] * att_edge[l, h, c]
__global__ void precompute_M(const void* __restrict__ lin_edge_W,
                             const void* __restrict__ att_edge,
                             float* __restrict__ Mbuf, const int* __restrict__ flags) {
    int isbf = flags[1];
    int tid = threadIdx.x;  // 512: l=tid>>8, h=(tid>>6)&3, c=tid&63
    int l = tid >> 8;
    int hc = tid & 255;
    float ae = ldx(att_edge, l * 256 + hc, isbf);
    size_t base = ((size_t)l * 256 + hc) * 3;
    float p0 = ae * ldx(lin_edge_W, base + 0, isbf);
    float p1 = ae * ldx(lin_edge_W, base + 1, isbf);
    float p2 = ae * ldx(lin_edge_W, base + 2, isbf);
    for (int off = 32; off > 0; off >>= 1) {
        p0 += __shfl_down(p0, off);
        p1 += __shfl_down(p1, off);
        p2 += __shfl_down(p2, off);
    }
    if ((tid & 63) == 0) {
        int h = (tid >> 6) & 3;
        Mbuf[(l * 4 + h) * 3 + 0] = p0;
        Mbuf[(l * 4 + h) * 3 + 1] = p1;
        Mbuf[(l * 4 + h) * 3 + 2] = p2;
    }
}

// 64 nodes per block. Weight row in registers (one output channel per thread),
// z tile in LDS. Computes x (bf16), a_src/a_dst, inits out_acc(=bias), denom(=0).
__global__ __launch_bounds__(256) void node_linear(
    const void* __restrict__ h_in,    // layer 0 input (generic dtype)
    const float* __restrict__ zprev,  // layer>0 input (f32, == out_acc)
    const void* __restrict__ lin_W,   // L*256*64
    const void* __restrict__ att_src, const void* __restrict__ att_dst,
    const void* __restrict__ bias,    // L*64
    ushort_t* __restrict__ xb,        // N*256 bf16
    float* __restrict__ a_src, float* __restrict__ a_dst,
    float* __restrict__ out_acc,      // N*64
    float* __restrict__ denom,        // N*4
    const int* __restrict__ flags, int layer) {
    __shared__ float zsh[MTILE * 64];
    int isbf = flags[1];
    int tid = threadIdx.x;
    int base = blockIdx.x * MTILE;
    int nnodes = NN - base < MTILE ? NN - base : MTILE;
    // stage z tile (reads out_acc in-place for layer>0: same block's nodes only)
    for (int i = tid; i < nnodes * 64; i += 256) {
        zsh[i] = (layer == 0) ? ldx(h_in, (size_t)base * 64 + i, isbf)
                              : zprev[(size_t)base * 64 + i];
    }
    // this thread's weight row -> 64 f32 registers
    float w[64];
    size_t wrow = ((size_t)layer * 256 + tid) * 64;
    if (isbf) {
        const uint_t* wr = (const uint_t*)((const ushort_t*)lin_W + wrow);
#pragma unroll
        for (int i = 0; i < 32; ++i) {
            uint_t p = wr[i];
            w[2 * i] = __uint_as_float(p << 16);
            w[2 * i + 1] = __uint_as_float(p & 0xffff0000u);
        }
    } else {
        const float* wr = (const float*)lin_W + wrow;
#pragma unroll
        for (int i = 0; i < 64; ++i) w[i] = wr[i];
    }
    float ats = ldx(att_src, layer * 256 + tid, isbf);
    float atd = ldx(att_dst, layer * 256 + tid, isbf);
    __syncthreads();
    int head = tid >> 6;  // == wave id; channels [64*head, 64*head+64)
    int lane = tid & 63;
    for (int nn = 0; nn < nnodes; ++nn) {
        const float4* zr = (const float4*)&zsh[nn * 64];
        float acc = 0.f;
#pragma unroll
        for (int kk = 0; kk < 16; ++kk) {
            float4 zv = zr[kk];
            acc += zv.x * w[4 * kk] + zv.y * w[4 * kk + 1] +
                   zv.z * w[4 * kk + 2] + zv.w * w[4 * kk + 3];
        }
        int n = base + nn;
        xb[(size_t)n * 256 + tid] = f2bf(acc);
        float ps = acc * ats, pd = acc * atd;
        for (int off = 32; off > 0; off >>= 1) {
            ps += __shfl_down(ps, off);
            pd += __shfl_down(pd, off);
        }
        if (lane == 0) {
            a_src[n * 4 + head] = ps;
            a_dst[n * 4 + head] = pd;
        }
    }
    for (int i = tid; i < nnodes * 64; i += 256)
        out_acc[(size_t)base * 64 + i] = ldx(bias, layer * 64 + (i & 63), isbf);
    if (tid < nnodes * 4) denom[base * 4 + tid] = 0.f;
}

// Per edge: ex = exp(leakyrelu(a_src[src]+a_dst[dst]+edge_attr@M^T)) (no max
// subtraction -- mathematically identical softmax; clamp at 80 guards inf).
// Stores ex, atomicAdds denom.
__global__ __launch_bounds__(256) void edge_pass1(
    const int* __restrict__ ei, const void* __restrict__ edge_attr,
    const float* __restrict__ a_src, const float* __restrict__ a_dst,
    const float* __restrict__ Mbuf, float* __restrict__ exbuf,
    float* __restrict__ denom, const int* __restrict__ flags, int layer) {
    __shared__ float Msh[12];
    if (threadIdx.x < 12) Msh[threadIdx.x] = Mbuf[layer * 12 + threadIdx.x];
    __syncthreads();
    int e = blockIdx.x * 256 + threadIdx.x;
    int f64 = flags[0], isbf = flags[1];
    int src = ld_src(ei, e, f64), dst = ld_dst(ei, e, f64);
    float4 as4 = *(const float4*)(a_src + (size_t)src * 4);
    float4 ad4 = *(const float4*)(a_dst + (size_t)dst * 4);
    float ea0 = ldx(edge_attr, (size_t)e * 3 + 0, isbf);
    float ea1 = ldx(edge_attr, (size_t)e * 3 + 1, isbf);
    float ea2 = ldx(edge_attr, (size_t)e * 3 + 2, isbf);
    float asv[4] = {as4.x, as4.y, as4.z, as4.w};
    float adv[4] = {ad4.x, ad4.y, ad4.z, ad4.w};
    float v[4];
#pragma unroll
    for (int h = 0; h < 4; ++h) {
        float t = asv[h] + adv[h] + ea0 * Msh[h * 3] + ea1 * Msh[h * 3 + 1] +
                  ea2 * Msh[h * 3 + 2];
        t = t > 0.f ? t : NEG_SLOPE * t;
        float ex = __expf(fminf(t, 80.f));
        v[h] = ex;
        atomicAdd(&denom[(size_t)dst * 4 + h], ex);
    }
    *(float4*)(exbuf + (size_t)e * 4) = make_float4(v[0], v[1], v[2], v[3]);
}

// Per (edge, channel): out_acc[dst,c] += 0.25 * sum_h w[e,h] * x[src, h*64+c]
__global__ __launch_bounds__(256) void edge_scatter(
    const int* __restrict__ ei, const float* __restrict__ exbuf,
    const float* __restrict__ denom, const ushort_t* __restrict__ xb,
    float* __restrict__ out_acc, const int* __restrict__ flags) {
    uint_t idx = blockIdx.x * 256u + threadIdx.x;
    int e = (int)(idx >> 6);
    int c = (int)(idx & 63u);
    int f64 = flags[0];
    int src = ld_src(ei, e, f64), dst = ld_dst(ei, e, f64);
    float4 ex = *(const float4*)(exbuf + (size_t)e * 4);
    float4 dn = *(const float4*)(denom + (size_t)dst * 4);
    float w0 = ex.x / (dn.x + 1e-16f);
    float w1 = ex.y / (dn.y + 1e-16f);
    float w2 = ex.z / (dn.z + 1e-16f);
    float w3 = ex.w / (dn.w + 1e-16f);
    const ushort_t* xr = xb + (size_t)src * 256;
    float val = 0.25f * (w0 * bf2f(xr[c]) + w1 * bf2f(xr[64 + c]) +
                         w2 * bf2f(xr[128 + c]) + w3 * bf2f(xr[192 + c]));
    atomicAdd(&out_acc[(size_t)dst * 64 + c], val);
}

// One wave per node: LayerNorm over 64 channels + SiLU.
// Not-last: writes z in-place into out_acc. Last: writes output (dtype per flags).
__global__ __launch_bounds__(256) void node_finish(
    float* __restrict__ out_acc, const void* __restrict__ gamma,
    const void* __restrict__ beta, void* __restrict__ outp,
    const int* __restrict__ flags, int layer, int last) {
    int isbf = flags[1];
    int node = blockIdx.x * 4 + (threadIdx.x >> 6);
    int lane = threadIdx.x & 63;
    size_t idx = (size_t)node * 64 + lane;
    float v = out_acc[idx];
    float s = v;
    for (int off = 1; off < 64; off <<= 1) s += __shfl_xor(s, off);
    float mu = s * (1.f / 64.f);
    float d = v - mu;
    float vv = d * d;
    for (int off = 1; off < 64; off <<= 1) vv += __shfl_xor(vv, off);
    float var = vv * (1.f / 64.f);
    float ln = d * rsqrtf(var + LN_EPS) * ldx(gamma, layer * 64 + lane, isbf) +
               ldx(beta, layer * 64 + lane, isbf);
    float sl = ln / (1.f + __expf(-ln));
    if (last) {
        if (isbf) ((ushort_t*)outp)[idx] = f2bf(sl);
        else      ((float*)outp)[idx] = sl;
    } else {
        out_acc[idx] = sl;
    }
}

extern "C" void kernel_launch(void* const* d_in, const int* in_sizes, int n_in,
                              void* d_out, int out_size, void* d_ws, size_t ws_size,
                              hipStream_t stream) {
    int off = (in_sizes[0] == 1) ? 1 : 0;
    const void* h_in  = d_in[off + 0];
    const int*  ei    = (const int*)d_in[off + 1];
    const void* eattr = d_in[off + 2];
    const void* linW  = d_in[off + 3];
    const void* linEW = d_in[off + 4];
    const void* attS  = d_in[off + 5];
    const void* attD  = d_in[off + 6];
    const void* attE  = d_in[off + 7];
    const void* bias  = d_in[off + 8];
    const void* gamma = d_in[off + 9];
    const void* beta  = d_in[off + 10];

    // workspace layout (~53.6 MB total; fits the limit that 54.4 MB satisfied)
    char* w = (char*)d_ws;
    int*    flags  = (int*)w;                              // 2 ints
    float*  Mbuf   = (float*)(w + 64);                     // 24 f32
    float*  a_src  = (float*)(w + 4096);                   // N*4 f32
    float*  a_dst  = a_src + (size_t)NN * 4;
    float*  denom  = a_dst + (size_t)NN * 4;
    float*  outacc = denom + (size_t)NN * 4;               // N*64 f32 (doubles as z)
    float*  exbuf  = outacc + (size_t)NN * 64;             // E*4 f32
    ushort_t* xb   = (ushort_t*)(exbuf + (size_t)NE * 4);  // N*256 bf16

    detect_flags<<<1, 64, 0, stream>>>(ei, h_in, flags);
    precompute_M<<<1, 512, 0, stream>>>(linEW, attE, Mbuf, flags);
    int nblocks = (NN + MTILE - 1) / MTILE;  // 782
    for (int l = 0; l < 2; ++l) {
        node_linear<<<nblocks, 256, 0, stream>>>(h_in, outacc, linW, attS, attD,
                                                 bias, xb, a_src, a_dst, outacc,
                                                 denom, flags, l);
        edge_pass1<<<NE / 256, 256, 0, stream>>>(ei, eattr, a_src, a_dst, Mbuf,
                                                 exbuf, denom, flags, l);
        edge_scatter<<<(NE * 64) / 256, 256, 0, stream>>>(ei, exbuf, denom, xb,
                                                          outacc, flags);
        node_finish<<<NN / 4, 256, 0, stream>>>(outacc, gamma, beta, d_out,
                                                flags, l, l == 1);
    }
}

// Round 5
// 525.951 us; speedup vs baseline: 3.4474x; 1.9042x over previous
//
#include <hip/hip_runtime.h>
#include <math.h>

#define NN 50000
#define NE 800000
#define NEG_SLOPE 0.2f
#define LN_EPS 1e-5f
#define MTILE 64

typedef unsigned short ushort_t;
typedef unsigned int uint_t;

__device__ __forceinline__ float bf2f(ushort_t u) {
    return __uint_as_float(((uint_t)u) << 16);
}
__device__ __forceinline__ ushort_t f2bf(float f) {
    uint_t b = __float_as_uint(f);
    uint_t r = (b + 0x7fffu + ((b >> 16) & 1u)) >> 16;
    return (ushort_t)r;
}
// generic float-input load: isbf ? bf16[i] : f32[i]
__device__ __forceinline__ float ldx(const void* p, size_t i, int isbf) {
    return isbf ? bf2f(((const ushort_t*)p)[i]) : ((const float*)p)[i];
}
__device__ __forceinline__ int clampN(int v) {
    return v < 0 ? 0 : (v >= NN ? NN - 1 : v);
}
// edge-index loads, robust to int64 storage (low word holds value)
__device__ __forceinline__ int ld_src(const int* ei, int e, int f64) {
    return clampN(f64 ? ei[2 * e] : ei[e]);
}
__device__ __forceinline__ int ld_dst(const int* ei, int e, int f64) {
    return clampN(f64 ? ei[2 * NE + 2 * e] : ei[NE + e]);
}

// flags[0] = edge_index-is-int64, flags[1] = floats-are-bf16
__global__ void detect_flags(const int* __restrict__ ei, const void* __restrict__ hptr,
                             int* __restrict__ flags) {
    if (threadIdx.x != 0) return;
    flags[0] = (ei[1] == 0 && ei[3] == 0 && ei[5] == 0 && ei[7] == 0) ? 1 : 0;
    const ushort_t* hu = (const ushort_t*)hptr;
    int bf = 1;
    for (int i = 0; i < 512; i += 2) {
        uint_t ex = (hu[i] >> 7) & 0xFFu;
        if (ex > 0x8Cu) bf = 0;  // |v| >= ~1e4 -> not bf16 data
    }
    flags[1] = bf;
}

// M[l][h][d] = sum_c lin_edge_W[l, h*64+c, d] * att_edge[l, h, c]
__global__ void precompute_M(const void* __restrict__ lin_edge_W,
                             const void* __restrict__ att_edge,
                             float* __restrict__ Mbuf, const int* __restrict__ flags) {
    int isbf = flags[1];
    int tid = threadIdx.x;  // 512: l=tid>>8, h=(tid>>6)&3, c=tid&63
    int l = tid >> 8;
    int hc = tid & 255;
    float ae = ldx(att_edge, l * 256 + hc, isbf);
    size_t base = ((size_t)l * 256 + hc) * 3;
    float p0 = ae * ldx(lin_edge_W, base + 0, isbf);
    float p1 = ae * ldx(lin_edge_W, base + 1, isbf);
    float p2 = ae * ldx(lin_edge_W, base + 2, isbf);
    for (int off = 32; off > 0; off >>= 1) {
        p0 += __shfl_down(p0, off);
        p1 += __shfl_down(p1, off);
        p2 += __shfl_down(p2, off);
    }
    if ((tid & 63) == 0) {
        int h = (tid >> 6) & 3;
        Mbuf[(l * 4 + h) * 3 + 0] = p0;
        Mbuf[(l * 4 + h) * 3 + 1] = p1;
        Mbuf[(l * 4 + h) * 3 + 2] = p2;
    }
}

// ---------------- CSR build (once per launch; graph static across layers) ----

__global__ void csr_zero(int* __restrict__ deg, int* __restrict__ cursor) {
    int i = blockIdx.x * 256 + threadIdx.x;
    if (i < NN) { deg[i] = 0; cursor[i] = 0; }
}

__global__ void csr_hist(const int* __restrict__ ei, int* __restrict__ deg,
                         const int* __restrict__ flags) {
    int e = blockIdx.x * 256 + threadIdx.x;
    if (e >= NE) return;
    atomicAdd(&deg[ld_dst(ei, e, flags[0])], 1);
}

// block-level exclusive scan of deg -> rowptr; per-block totals -> bsum
__global__ __launch_bounds__(1024) void csr_scan1(const int* __restrict__ deg,
                                                  int* __restrict__ rowptr,
                                                  int* __restrict__ bsum) {
    __shared__ int sh[1024];
    int i = blockIdx.x * 1024 + threadIdx.x;
    int v = (i < NN) ? deg[i] : 0;
    sh[threadIdx.x] = v;
    __syncthreads();
    for (int off = 1; off < 1024; off <<= 1) {
        int t = (threadIdx.x >= off) ? sh[threadIdx.x - off] : 0;
        __syncthreads();
        sh[threadIdx.x] += t;
        __syncthreads();
    }
    if (i < NN) rowptr[i] = sh[threadIdx.x] - v;  // exclusive within block
    if (threadIdx.x == 1023) bsum[blockIdx.x] = sh[1023];
}

__global__ void csr_scan2(int* __restrict__ bsum, int nb) {
    if (threadIdx.x != 0) return;
    int run = 0;
    for (int b = 0; b < nb; ++b) {
        int t = bsum[b];
        bsum[b] = run;
        run += t;
    }
}

__global__ __launch_bounds__(1024) void csr_scan3(int* __restrict__ rowptr,
                                                  const int* __restrict__ bsum) {
    int i = blockIdx.x * 1024 + threadIdx.x;
    if (i < NN) rowptr[i] += bsum[blockIdx.x];
    if (i == 0) rowptr[NN] = NE;
}

// edata[pos] = {ea0, ea1, ea2, src-as-bits}, pos grouped by dst
__global__ void csr_fill(const int* __restrict__ ei, const void* __restrict__ edge_attr,
                         const int* __restrict__ rowptr, int* __restrict__ cursor,
                         float4* __restrict__ edata, const int* __restrict__ flags) {
    int e = blockIdx.x * 256 + threadIdx.x;
    if (e >= NE) return;
    int f64 = flags[0], isbf = flags[1];
    int s = ld_src(ei, e, f64), d = ld_dst(ei, e, f64);
    int pos = rowptr[d] + atomicAdd(&cursor[d], 1);
    float4 ed;
    ed.x = ldx(edge_attr, (size_t)e * 3 + 0, isbf);
    ed.y = ldx(edge_attr, (size_t)e * 3 + 1, isbf);
    ed.z = ldx(edge_attr, (size_t)e * 3 + 2, isbf);
    ed.w = __int_as_float(s);
    edata[pos] = ed;
}

// ---------------- per-layer kernels ----------------------------------------

// 64 nodes per block. Weight row in registers (one output channel per thread),
// z tile in LDS. Computes x (bf16, layout [n][c*4+h]) and a_src/a_dst.
__global__ __launch_bounds__(256) void node_linear(
    const void* __restrict__ h_in,    // layer 0 input (generic dtype)
    const float* __restrict__ zprev,  // layer>0 input (f32)
    const void* __restrict__ lin_W,   // L*256*64
    const void* __restrict__ att_src, const void* __restrict__ att_dst,
    ushort_t* __restrict__ xb,        // N*256 bf16, [n][c*4+h]
    float* __restrict__ a_src, float* __restrict__ a_dst,
    const int* __restrict__ flags, int layer) {
    __shared__ float zsh[MTILE * 64];
    int isbf = flags[1];
    int tid = threadIdx.x;
    int base = blockIdx.x * MTILE;
    int nnodes = NN - base < MTILE ? NN - base : MTILE;
    for (int i = tid; i < nnodes * 64; i += 256) {
        zsh[i] = (layer == 0) ? ldx(h_in, (size_t)base * 64 + i, isbf)
                              : zprev[(size_t)base * 64 + i];
    }
    float w[64];
    size_t wrow = ((size_t)layer * 256 + tid) * 64;
    if (isbf) {
        const uint_t* wr = (const uint_t*)((const ushort_t*)lin_W + wrow);
#pragma unroll
        for (int i = 0; i < 32; ++i) {
            uint_t p = wr[i];
            w[2 * i] = __uint_as_float(p << 16);
            w[2 * i + 1] = __uint_as_float(p & 0xffff0000u);
        }
    } else {
        const float* wr = (const float*)lin_W + wrow;
#pragma unroll
        for (int i = 0; i < 64; ++i) w[i] = wr[i];
    }
    float ats = ldx(att_src, layer * 256 + tid, isbf);
    float atd = ldx(att_dst, layer * 256 + tid, isbf);
    __syncthreads();
    int head = tid >> 6;  // wave id; this thread owns channel (head, lane)
    int lane = tid & 63;
    for (int nn = 0; nn < nnodes; ++nn) {
        const float4* zr = (const float4*)&zsh[nn * 64];
        float acc = 0.f;
#pragma unroll
        for (int kk = 0; kk < 16; ++kk) {
            float4 zv = zr[kk];
            acc += zv.x * w[4 * kk] + zv.y * w[4 * kk + 1] +
                   zv.z * w[4 * kk + 2] + zv.w * w[4 * kk + 3];
        }
        int n = base + nn;
        xb[(size_t)n * 256 + lane * 4 + head] = f2bf(acc);
        float ps = acc * ats, pd = acc * atd;
        for (int off = 32; off > 0; off >>= 1) {
            ps += __shfl_down(ps, off);
            pd += __shfl_down(pd, off);
        }
        if (lane == 0) {
            a_src[n * 4 + head] = ps;
            a_dst[n * 4 + head] = pd;
        }
    }
}

// One wave per node: softmax-weighted neighbor aggregation (no atomics, no
// max-subtraction -- exact segment sums via CSR), head-mean + bias, LayerNorm,
// SiLU, write z (or final output).
__global__ __launch_bounds__(256) void node_aggregate(
    const int* __restrict__ rowptr, const float4* __restrict__ edata,
    const float* __restrict__ a_src, const float* __restrict__ a_dst,
    const ushort_t* __restrict__ xb, const float* __restrict__ Mbuf,
    const void* __restrict__ bias, const void* __restrict__ gamma,
    const void* __restrict__ beta, float* __restrict__ zout,
    void* __restrict__ outp, const int* __restrict__ flags, int layer, int last) {
    int isbf = flags[1];
    int n = blockIdx.x * 4 + (threadIdx.x >> 6);
    int lane = threadIdx.x & 63;
    float M[12];
#pragma unroll
    for (int i = 0; i < 12; ++i) M[i] = Mbuf[layer * 12 + i];
    float4 ad = *(const float4*)(a_dst + (size_t)n * 4);
    int start = rowptr[n], end = rowptr[n + 1];
    float acc0 = 0.f, acc1 = 0.f, acc2 = 0.f, acc3 = 0.f;
    float den0 = 0.f, den1 = 0.f, den2 = 0.f, den3 = 0.f;
    for (int cb = start; cb < end; cb += 64) {
        int m = end - cb;
        if (m > 64) m = 64;
        float ex0 = 0.f, ex1 = 0.f, ex2 = 0.f, ex3 = 0.f;
        int s = 0;
        if (lane < m) {
            float4 ed = edata[cb + lane];
            s = __float_as_int(ed.w);
            float4 as4 = *(const float4*)(a_src + (size_t)s * 4);
            float t0 = as4.x + ad.x + ed.x * M[0] + ed.y * M[1] + ed.z * M[2];
            float t1 = as4.y + ad.y + ed.x * M[3] + ed.y * M[4] + ed.z * M[5];
            float t2 = as4.z + ad.z + ed.x * M[6] + ed.y * M[7] + ed.z * M[8];
            float t3 = as4.w + ad.w + ed.x * M[9] + ed.y * M[10] + ed.z * M[11];
            t0 = t0 > 0.f ? t0 : NEG_SLOPE * t0;
            t1 = t1 > 0.f ? t1 : NEG_SLOPE * t1;
            t2 = t2 > 0.f ? t2 : NEG_SLOPE * t2;
            t3 = t3 > 0.f ? t3 : NEG_SLOPE * t3;
            ex0 = __expf(fminf(t0, 80.f));
            ex1 = __expf(fminf(t1, 80.f));
            ex2 = __expf(fminf(t2, 80.f));
            ex3 = __expf(fminf(t3, 80.f));
            den0 += ex0; den1 += ex1; den2 += ex2; den3 += ex3;
        }
        for (int j = 0; j < m; ++j) {
            int sj = __shfl(s, j);
            float w0 = __shfl(ex0, j), w1 = __shfl(ex1, j);
            float w2 = __shfl(ex2, j), w3 = __shfl(ex3, j);
            ushort4 xv = *(const ushort4*)(xb + (size_t)sj * 256 + lane * 4);
            acc0 += w0 * bf2f(xv.x);
            acc1 += w1 * bf2f(xv.y);
            acc2 += w2 * bf2f(xv.z);
            acc3 += w3 * bf2f(xv.w);
        }
    }
    for (int off = 1; off < 64; off <<= 1) {
        den0 += __shfl_xor(den0, off);
        den1 += __shfl_xor(den1, off);
        den2 += __shfl_xor(den2, off);
        den3 += __shfl_xor(den3, off);
    }
    float v = ldx(bias, layer * 64 + lane, isbf) +
              0.25f * (acc0 / (den0 + 1e-16f) + acc1 / (den1 + 1e-16f) +
                       acc2 / (den2 + 1e-16f) + acc3 / (den3 + 1e-16f));
    // LayerNorm over the 64 lanes + SiLU
    float sum = v;
    for (int off = 1; off < 64; off <<= 1) sum += __shfl_xor(sum, off);
    float mu = sum * (1.f / 64.f);
    float d = v - mu;
    float vv = d * d;
    for (int off = 1; off < 64; off <<= 1) vv += __shfl_xor(vv, off);
    float var = vv * (1.f / 64.f);
    float ln = d * rsqrtf(var + LN_EPS) * ldx(gamma, layer * 64 + lane, isbf) +
               ldx(beta, layer * 64 + lane, isbf);
    float sl = ln / (1.f + __expf(-ln));
    size_t idx = (size_t)n * 64 + lane;
    if (last) {
        if (isbf) ((ushort_t*)outp)[idx] = f2bf(sl);
        else      ((float*)outp)[idx] = sl;
    } else {
        zout[idx] = sl;
    }
}

extern "C" void kernel_launch(void* const* d_in, const int* in_sizes, int n_in,
                              void* d_out, int out_size, void* d_ws, size_t ws_size,
                              hipStream_t stream) {
    int off = (in_sizes[0] == 1) ? 1 : 0;
    const void* h_in  = d_in[off + 0];
    const int*  ei    = (const int*)d_in[off + 1];
    const void* eattr = d_in[off + 2];
    const void* linW  = d_in[off + 3];
    const void* linEW = d_in[off + 4];
    const void* attS  = d_in[off + 5];
    const void* attD  = d_in[off + 6];
    const void* attE  = d_in[off + 7];
    const void* bias  = d_in[off + 8];
    const void* gamma = d_in[off + 9];
    const void* beta  = d_in[off + 10];

    // bump allocator, 256 B aligned (~53.6 MB total)
    char* w = (char*)d_ws;
    size_t o = 0;
    auto alloc = [&](size_t bytes) {
        void* p = w + o;
        o += (bytes + 255) & ~(size_t)255;
        return p;
    };
    int*    flags  = (int*)alloc(8);
    float*  Mbuf   = (float*)alloc(24 * 4);
    float*  a_src  = (float*)alloc((size_t)NN * 4 * 4);
    float*  a_dst  = (float*)alloc((size_t)NN * 4 * 4);
    int*    rowptr = (int*)alloc((size_t)(NN + 1) * 4);
    int*    deg    = (int*)alloc((size_t)NN * 4);
    int*    cursor = (int*)alloc((size_t)NN * 4);
    int*    bsum   = (int*)alloc(64 * 4);
    float*  zbuf   = (float*)alloc((size_t)NN * 64 * 4);
    ushort_t* xb   = (ushort_t*)alloc((size_t)NN * 256 * 2);
    float4* edata  = (float4*)alloc((size_t)NE * 16);

    detect_flags<<<1, 64, 0, stream>>>(ei, h_in, flags);
    precompute_M<<<1, 512, 0, stream>>>(linEW, attE, Mbuf, flags);
    // CSR build (graph is static across both layers)
    int nb = (NN + 1023) / 1024;  // 49
    csr_zero<<<(NN + 255) / 256, 256, 0, stream>>>(deg, cursor);
    csr_hist<<<(NE + 255) / 256, 256, 0, stream>>>(ei, deg, flags);
    csr_scan1<<<nb, 1024, 0, stream>>>(deg, rowptr, bsum);
    csr_scan2<<<1, 64, 0, stream>>>(bsum, nb);
    csr_scan3<<<nb, 1024, 0, stream>>>(rowptr, bsum);
    csr_fill<<<(NE + 255) / 256, 256, 0, stream>>>(ei, eattr, rowptr, cursor, edata, flags);

    int nlb = (NN + MTILE - 1) / MTILE;  // 782
    for (int l = 0; l < 2; ++l) {
        node_linear<<<nlb, 256, 0, stream>>>(h_in, zbuf, linW, attS, attD,
                                             xb, a_src, a_dst, flags, l);
        node_aggregate<<<NN / 4, 256, 0, stream>>>(rowptr, edata, a_src, a_dst,
                                                   xb, Mbuf, bias, gamma, beta,
                                                   zbuf, d_out, flags, l, l == 1);
    }
}

// Round 6
// 495.907 us; speedup vs baseline: 3.6563x; 1.0606x over previous
//
#include <hip/hip_runtime.h>
#include <math.h>

#define NN 50000
#define NE 800000
#define NEG_SLOPE 0.2f
#define LN_EPS 1e-5f
#define MTILE 64

typedef unsigned short ushort_t;
typedef unsigned int uint_t;
typedef __attribute__((ext_vector_type(8))) short bf16x8;
typedef __attribute__((ext_vector_type(4))) float f32x4;

__device__ __forceinline__ float bf2f(ushort_t u) {
    return __uint_as_float(((uint_t)u) << 16);
}
__device__ __forceinline__ ushort_t f2bf(float f) {
    uint_t b = __float_as_uint(f);
    uint_t r = (b + 0x7fffu + ((b >> 16) & 1u)) >> 16;
    return (ushort_t)r;
}
// generic float-input load: isbf ? bf16[i] : f32[i]
__device__ __forceinline__ float ldx(const void* p, size_t i, int isbf) {
    return isbf ? bf2f(((const ushort_t*)p)[i]) : ((const float*)p)[i];
}
__device__ __forceinline__ int clampN(int v) {
    return v < 0 ? 0 : (v >= NN ? NN - 1 : v);
}
// edge-index loads, robust to int64 storage (low word holds value)
__device__ __forceinline__ int ld_src(const int* ei, int e, int f64) {
    return clampN(f64 ? ei[2 * e] : ei[e]);
}
__device__ __forceinline__ int ld_dst(const int* ei, int e, int f64) {
    return clampN(f64 ? ei[2 * NE + 2 * e] : ei[NE + e]);
}

// flags[0] = edge_index-is-int64, flags[1] = floats-are-bf16
__global__ void detect_flags(const int* __restrict__ ei, const void* __restrict__ hptr,
                             int* __restrict__ flags) {
    if (threadIdx.x != 0) return;
    flags[0] = (ei[1] == 0 && ei[3] == 0 && ei[5] == 0 && ei[7] == 0) ? 1 : 0;
    const ushort_t* hu = (const ushort_t*)hptr;
    int bf = 1;
    for (int i = 0; i < 512; i += 2) {
        uint_t ex = (hu[i] >> 7) & 0xFFu;
        if (ex > 0x8Cu) bf = 0;  // |v| >= ~1e4 -> not bf16 data
    }
    flags[1] = bf;
}

// M[l][h][d] = sum_c lin_edge_W[l, h*64+c, d] * att_edge[l, h, c]
__global__ void precompute_M(const void* __restrict__ lin_edge_W,
                             const void* __restrict__ att_edge,
                             float* __restrict__ Mbuf, const int* __restrict__ flags) {
    int isbf = flags[1];
    int tid = threadIdx.x;  // 512: l=tid>>8, h=(tid>>6)&3, c=tid&63
    int l = tid >> 8;
    int hc = tid & 255;
    float ae = ldx(att_edge, l * 256 + hc, isbf);
    size_t base = ((size_t)l * 256 + hc) * 3;
    float p0 = ae * ldx(lin_edge_W, base + 0, isbf);
    float p1 = ae * ldx(lin_edge_W, base + 1, isbf);
    float p2 = ae * ldx(lin_edge_W, base + 2, isbf);
    for (int off = 32; off > 0; off >>= 1) {
        p0 += __shfl_down(p0, off);
        p1 += __shfl_down(p1, off);
        p2 += __shfl_down(p2, off);
    }
    if ((tid & 63) == 0) {
        int h = (tid >> 6) & 3;
        Mbuf[(l * 4 + h) * 3 + 0] = p0;
        Mbuf[(l * 4 + h) * 3 + 1] = p1;
        Mbuf[(l * 4 + h) * 3 + 2] = p2;
    }
}

// W_ext[l][272][64] bf16: rows 0..255 = lin_W rows; 256..259 = u_src[h];
// 260..263 = u_dst[h]; 264..271 = 0.  u_src[h][d] = sum_c W[h*64+c][d]*att_src[h][c]
// => a_src[n,h] = z[n,:]  u_src[h] folds the attention reduction into the GEMM.
__global__ void precompute_W(const void* __restrict__ lin_W,
                             const void* __restrict__ att_src,
                             const void* __restrict__ att_dst,
                             ushort_t* __restrict__ wext,
                             const int* __restrict__ flags) {
    int isbf = flags[1];
    int idx = blockIdx.x * 256 + threadIdx.x;  // 2*272*64 = 34816
    if (idx >= 2 * 272 * 64) return;
    int d = idx & 63;
    int row = (idx >> 6) % 272;
    int l = idx / (272 * 64);
    float v = 0.f;
    if (row < 256) {
        v = ldx(lin_W, ((size_t)l * 256 + row) * 64 + d, isbf);
    } else if (row < 264) {
        int h = (row - 256) & 3;
        const void* att = (row < 260) ? att_src : att_dst;
        for (int c = 0; c < 64; ++c) {
            v += ldx(lin_W, ((size_t)l * 256 + h * 64 + c) * 64 + d, isbf) *
                 ldx(att, l * 256 + h * 64 + c, isbf);
        }
    }
    wext[((size_t)l * 272 + row) * 64 + d] = f2bf(v);
}

// ---------------- CSR build (once per launch; graph static across layers) ----

__global__ void csr_zero(int* __restrict__ deg) {
    int i = blockIdx.x * 256 + threadIdx.x;
    if (i < NN) deg[i] = 0;
}

// histogram + per-edge slot in one pass
__global__ void csr_hist_pos(const int* __restrict__ ei, int* __restrict__ deg,
                             int* __restrict__ pos, const int* __restrict__ flags) {
    int e = blockIdx.x * 256 + threadIdx.x;
    if (e >= NE) return;
    pos[e] = atomicAdd(&deg[ld_dst(ei, e, flags[0])], 1);
}

// block-level exclusive scan of deg -> rowptr; per-block totals -> bsum
__global__ __launch_bounds__(1024) void csr_scan1(const int* __restrict__ deg,
                                                  int* __restrict__ rowptr,
                                                  int* __restrict__ bsum) {
    __shared__ int sh[1024];
    int i = blockIdx.x * 1024 + threadIdx.x;
    int v = (i < NN) ? deg[i] : 0;
    sh[threadIdx.x] = v;
    __syncthreads();
    for (int off = 1; off < 1024; off <<= 1) {
        int t = (threadIdx.x >= off) ? sh[threadIdx.x - off] : 0;
        __syncthreads();
        sh[threadIdx.x] += t;
        __syncthreads();
    }
    if (i < NN) rowptr[i] = sh[threadIdx.x] - v;
    if (threadIdx.x == 1023) bsum[blockIdx.x] = sh[1023];
}

__global__ void csr_scan2(int* __restrict__ bsum, int nb) {
    if (threadIdx.x != 0) return;
    int run = 0;
    for (int b = 0; b < nb; ++b) {
        int t = bsum[b];
        bsum[b] = run;
        run += t;
    }
}

__global__ __launch_bounds__(1024) void csr_scan3(int* __restrict__ rowptr,
                                                  const int* __restrict__ bsum) {
    int i = blockIdx.x * 1024 + threadIdx.x;
    if (i < NN) rowptr[i] += bsum[blockIdx.x];
    if (i == 0) rowptr[NN] = NE;
}

// edata[slot] = {ea0, ea1, ea2, src-as-bits}, slot grouped by dst
__global__ void csr_fill(const int* __restrict__ ei, const void* __restrict__ edge_attr,
                         const int* __restrict__ rowptr, const int* __restrict__ pos,
                         float4* __restrict__ edata, const int* __restrict__ flags) {
    int e = blockIdx.x * 256 + threadIdx.x;
    if (e >= NE) return;
    int f64 = flags[0], isbf = flags[1];
    int s = ld_src(ei, e, f64), d = ld_dst(ei, e, f64);
    float4 ed;
    ed.x = ldx(edge_attr, (size_t)e * 3 + 0, isbf);
    ed.y = ldx(edge_attr, (size_t)e * 3 + 1, isbf);
    ed.z = ldx(edge_attr, (size_t)e * 3 + 2, isbf);
    ed.w = __int_as_float(s);
    edata[rowptr[d] + pos[e]] = ed;
}

// ---------------- per-layer kernels ----------------------------------------

// bf16 path: pure MFMA GEMM [64 nodes x 64] @ [64 x 272] per block (4 waves x
// 16 nodes), no LDS, no shuffles. Cols 0..255 -> x (bf16, [n][c*4+h]);
// cols 256..263 -> a_src/a_dst (f32). f32 path: legacy VALU fallback.
__global__ __launch_bounds__(256) void node_linear(
    const void* __restrict__ h_in,   // layer 0 input
    const void* __restrict__ zprev,  // layer>0 input (bf16 if isbf else f32)
    const void* __restrict__ lin_W,
    const void* __restrict__ att_src, const void* __restrict__ att_dst,
    const ushort_t* __restrict__ wext,  // L*272*64 bf16
    ushort_t* __restrict__ xb,          // N*256 bf16, [n][c*4+h]
    float* __restrict__ a_src, float* __restrict__ a_dst,
    const int* __restrict__ flags, int layer) {
    __shared__ float zsh[MTILE * 64];
    int isbf = flags[1];
    int tid = threadIdx.x;
    if (isbf) {
        int wave = tid >> 6, lane = tid & 63;
        int q = lane >> 4, mi = lane & 15;
        int mbase = blockIdx.x * MTILE + wave * 16;
        int mnode = mbase + mi;
        int mld = mnode < NN ? mnode : NN - 1;  // clamped load; stores bounds-checked
        const ushort_t* zrow = (layer == 0)
            ? (const ushort_t*)h_in + (size_t)mld * 64
            : (const ushort_t*)zprev + (size_t)mld * 64;
        bf16x8 a0 = *(const bf16x8*)(zrow + q * 8);
        bf16x8 a1 = *(const bf16x8*)(zrow + 32 + q * 8);
        const ushort_t* wl = wext + (size_t)layer * 272 * 64;
        for (int t = 0; t < 17; ++t) {
            const ushort_t* wrow = wl + (size_t)(t * 16 + mi) * 64;
            bf16x8 b0 = *(const bf16x8*)(wrow + q * 8);
            bf16x8 b1 = *(const bf16x8*)(wrow + 32 + q * 8);
            f32x4 acc = {0.f, 0.f, 0.f, 0.f};
            acc = __builtin_amdgcn_mfma_f32_16x16x32_bf16(a0, b0, acc, 0, 0, 0);
            acc = __builtin_amdgcn_mfma_f32_16x16x32_bf16(a1, b1, acc, 0, 0, 0);
            int col = t * 16 + mi;  // C/D: col=lane&15, row=q*4+reg (m89)
#pragma unroll
            for (int r = 0; r < 4; ++r) {
                int node = mbase + q * 4 + r;
                if (node >= NN) continue;
                if (t < 16) {
                    xb[(size_t)node * 256 + (col & 63) * 4 + (col >> 6)] = f2bf(acc[r]);
                } else {
                    int j = col - 256;
                    if (j < 4) a_src[node * 4 + j] = acc[r];
                    else if (j < 8) a_dst[node * 4 + (j - 4)] = acc[r];
                }
            }
        }
        return;
    }
    // ---- f32 fallback (legacy path) ----
    int base = blockIdx.x * MTILE;
    int nnodes = NN - base < MTILE ? NN - base : MTILE;
    for (int i = tid; i < nnodes * 64; i += 256) {
        zsh[i] = (layer == 0) ? ((const float*)h_in)[(size_t)base * 64 + i]
                              : ((const float*)zprev)[(size_t)base * 64 + i];
    }
    float w[64];
    size_t wrow = ((size_t)layer * 256 + tid) * 64;
    const float* wr = (const float*)lin_W + wrow;
#pragma unroll
    for (int i = 0; i < 64; ++i) w[i] = wr[i];
    float ats = ((const float*)att_src)[layer * 256 + tid];
    float atd = ((const float*)att_dst)[layer * 256 + tid];
    __syncthreads();
    int head = tid >> 6;
    int lane = tid & 63;
    for (int nn = 0; nn < nnodes; ++nn) {
        const float4* zr = (const float4*)&zsh[nn * 64];
        float acc = 0.f;
#pragma unroll
        for (int kk = 0; kk < 16; ++kk) {
            float4 zv = zr[kk];
            acc += zv.x * w[4 * kk] + zv.y * w[4 * kk + 1] +
                   zv.z * w[4 * kk + 2] + zv.w * w[4 * kk + 3];
        }
        int n = base + nn;
        xb[(size_t)n * 256 + lane * 4 + head] = f2bf(acc);
        float ps = acc * ats, pd = acc * atd;
        for (int off = 32; off > 0; off >>= 1) {
            ps += __shfl_down(ps, off);
            pd += __shfl_down(pd, off);
        }
        if (lane == 0) {
            a_src[n * 4 + head] = ps;
            a_dst[n * 4 + head] = pd;
        }
    }
}

// One wave per node: softmax-weighted neighbor aggregation (no atomics),
// head-mean + bias, LayerNorm, SiLU. z written bf16 (isbf) or f32.
__global__ __launch_bounds__(256) void node_aggregate(
    const int* __restrict__ rowptr, const float4* __restrict__ edata,
    const float* __restrict__ a_src, const float* __restrict__ a_dst,
    const ushort_t* __restrict__ xb, const float* __restrict__ Mbuf,
    const void* __restrict__ bias, const void* __restrict__ gamma,
    const void* __restrict__ beta, void* __restrict__ zout,
    void* __restrict__ outp, const int* __restrict__ flags, int layer, int last) {
    int isbf = flags[1];
    int n = blockIdx.x * 4 + (threadIdx.x >> 6);
    int lane = threadIdx.x & 63;
    float M[12];
#pragma unroll
    for (int i = 0; i < 12; ++i) M[i] = Mbuf[layer * 12 + i];
    float4 ad = *(const float4*)(a_dst + (size_t)n * 4);
    int start = rowptr[n], end = rowptr[n + 1];
    float acc0 = 0.f, acc1 = 0.f, acc2 = 0.f, acc3 = 0.f;
    float den0 = 0.f, den1 = 0.f, den2 = 0.f, den3 = 0.f;
    for (int cb = start; cb < end; cb += 64) {
        int m = end - cb;
        if (m > 64) m = 64;
        float ex0 = 0.f, ex1 = 0.f, ex2 = 0.f, ex3 = 0.f;
        int s = 0;
        if (lane < m) {
            float4 ed = edata[cb + lane];
            s = __float_as_int(ed.w);
            float4 as4 = *(const float4*)(a_src + (size_t)s * 4);
            float t0 = as4.x + ad.x + ed.x * M[0] + ed.y * M[1] + ed.z * M[2];
            float t1 = as4.y + ad.y + ed.x * M[3] + ed.y * M[4] + ed.z * M[5];
            float t2 = as4.z + ad.z + ed.x * M[6] + ed.y * M[7] + ed.z * M[8];
            float t3 = as4.w + ad.w + ed.x * M[9] + ed.y * M[10] + ed.z * M[11];
            t0 = t0 > 0.f ? t0 : NEG_SLOPE * t0;
            t1 = t1 > 0.f ? t1 : NEG_SLOPE * t1;
            t2 = t2 > 0.f ? t2 : NEG_SLOPE * t2;
            t3 = t3 > 0.f ? t3 : NEG_SLOPE * t3;
            ex0 = __expf(fminf(t0, 80.f));
            ex1 = __expf(fminf(t1, 80.f));
            ex2 = __expf(fminf(t2, 80.f));
            ex3 = __expf(fminf(t3, 80.f));
            den0 += ex0; den1 += ex1; den2 += ex2; den3 += ex3;
        }
        for (int j = 0; j < m; ++j) {
            int sj = __shfl(s, j);
            float w0 = __shfl(ex0, j), w1 = __shfl(ex1, j);
            float w2 = __shfl(ex2, j), w3 = __shfl(ex3, j);
            ushort4 xv = *(const ushort4*)(xb + (size_t)sj * 256 + lane * 4);
            acc0 += w0 * bf2f(xv.x);
            acc1 += w1 * bf2f(xv.y);
            acc2 += w2 * bf2f(xv.z);
            acc3 += w3 * bf2f(xv.w);
        }
    }
    for (int off = 1; off < 64; off <<= 1) {
        den0 += __shfl_xor(den0, off);
        den1 += __shfl_xor(den1, off);
        den2 += __shfl_xor(den2, off);
        den3 += __shfl_xor(den3, off);
    }
    float v = ldx(bias, layer * 64 + lane, isbf) +
              0.25f * (acc0 / (den0 + 1e-16f) + acc1 / (den1 + 1e-16f) +
                       acc2 / (den2 + 1e-16f) + acc3 / (den3 + 1e-16f));
    float sum = v;
    for (int off = 1; off < 64; off <<= 1) sum += __shfl_xor(sum, off);
    float mu = sum * (1.f / 64.f);
    float d = v - mu;
    float vv = d * d;
    for (int off = 1; off < 64; off <<= 1) vv += __shfl_xor(vv, off);
    float var = vv * (1.f / 64.f);
    float ln = d * rsqrtf(var + LN_EPS) * ldx(gamma, layer * 64 + lane, isbf) +
               ldx(beta, layer * 64 + lane, isbf);
    float sl = ln / (1.f + __expf(-ln));
    size_t idx = (size_t)n * 64 + lane;
    if (last) {
        if (isbf) ((ushort_t*)outp)[idx] = f2bf(sl);
        else      ((float*)outp)[idx] = sl;
    } else {
        if (isbf) ((ushort_t*)zout)[idx] = f2bf(sl);
        else      ((float*)zout)[idx] = sl;
    }
}

extern "C" void kernel_launch(void* const* d_in, const int* in_sizes, int n_in,
                              void* d_out, int out_size, void* d_ws, size_t ws_size,
                              hipStream_t stream) {
    int off = (in_sizes[0] == 1) ? 1 : 0;
    const void* h_in  = d_in[off + 0];
    const int*  ei    = (const int*)d_in[off + 1];
    const void* eattr = d_in[off + 2];
    const void* linW  = d_in[off + 3];
    const void* linEW = d_in[off + 4];
    const void* attS  = d_in[off + 5];
    const void* attD  = d_in[off + 6];
    const void* attE  = d_in[off + 7];
    const void* bias  = d_in[off + 8];
    const void* gamma = d_in[off + 9];
    const void* beta  = d_in[off + 10];

    // bump allocator, 256 B aligned (~56.5 MB total)
    char* w = (char*)d_ws;
    size_t o = 0;
    auto alloc = [&](size_t bytes) {
        void* p = w + o;
        o += (bytes + 255) & ~(size_t)255;
        return p;
    };
    int*    flags  = (int*)alloc(8);
    float*  Mbuf   = (float*)alloc(24 * 4);
    ushort_t* wext = (ushort_t*)alloc((size_t)2 * 272 * 64 * 2);
    float*  a_src  = (float*)alloc((size_t)NN * 4 * 4);
    float*  a_dst  = (float*)alloc((size_t)NN * 4 * 4);
    int*    rowptr = (int*)alloc((size_t)(NN + 1) * 4);
    int*    deg    = (int*)alloc((size_t)NN * 4);
    int*    pos    = (int*)alloc((size_t)NE * 4);
    int*    bsum   = (int*)alloc(64 * 4);
    void*   zbuf   = alloc((size_t)NN * 64 * 4);  // f32-sized; bf16 when isbf
    ushort_t* xb   = (ushort_t*)alloc((size_t)NN * 256 * 2);
    float4* edata  = (float4*)alloc((size_t)NE * 16);

    detect_flags<<<1, 64, 0, stream>>>(ei, h_in, flags);
    precompute_M<<<1, 512, 0, stream>>>(linEW, attE, Mbuf, flags);
    precompute_W<<<136, 256, 0, stream>>>(linW, attS, attD, wext, flags);
    int nb = (NN + 1023) / 1024;  // 49
    csr_zero<<<(NN + 255) / 256, 256, 0, stream>>>(deg);
    csr_hist_pos<<<(NE + 255) / 256, 256, 0, stream>>>(ei, deg, pos, flags);
    csr_scan1<<<nb, 1024, 0, stream>>>(deg, rowptr, bsum);
    csr_scan2<<<1, 64, 0, stream>>>(bsum, nb);
    csr_scan3<<<nb, 1024, 0, stream>>>(rowptr, bsum);
    csr_fill<<<(NE + 255) / 256, 256, 0, stream>>>(ei, eattr, rowptr, pos, edata, flags);

    int nlb = (NN + MTILE - 1) / MTILE;  // 782
    for (int l = 0; l < 2; ++l) {
        node_linear<<<nlb, 256, 0, stream>>>(h_in, zbuf, linW, attS, attD, wext,
                                             xb, a_src, a_dst, flags, l);
        node_aggregate<<<NN / 4, 256, 0, stream>>>(rowptr, edata, a_src, a_dst,
                                                   xb, Mbuf, bias, gamma, beta,
                                                   zbuf, d_out, flags, l, l == 1);
    }
}

// Round 7
// 495.687 us; speedup vs baseline: 3.6579x; 1.0004x over previous
//
#include <hip/hip_runtime.h>
#include <math.h>

#define NN 50000
#define NE 800000
#define NEG_SLOPE 0.2f
#define LN_EPS 1e-5f
#define MTILE 64
#define SROW 264  // LDS stage row stride in ushorts (256 + 8 pad)

typedef unsigned short ushort_t;
typedef unsigned int uint_t;
typedef __attribute__((ext_vector_type(8))) short bf16x8;
typedef __attribute__((ext_vector_type(4))) float f32x4;

__device__ __forceinline__ float bf2f(ushort_t u) {
    return __uint_as_float(((uint_t)u) << 16);
}
__device__ __forceinline__ ushort_t f2bf(float f) {
    uint_t b = __float_as_uint(f);
    uint_t r = (b + 0x7fffu + ((b >> 16) & 1u)) >> 16;
    return (ushort_t)r;
}
// generic float-input load: isbf ? bf16[i] : f32[i]
__device__ __forceinline__ float ldx(const void* p, size_t i, int isbf) {
    return isbf ? bf2f(((const ushort_t*)p)[i]) : ((const float*)p)[i];
}
__device__ __forceinline__ int clampN(int v) {
    return v < 0 ? 0 : (v >= NN ? NN - 1 : v);
}
// edge-index loads, robust to int64 storage (low word holds value)
__device__ __forceinline__ int ld_src(const int* ei, int e, int f64) {
    return clampN(f64 ? ei[2 * e] : ei[e]);
}
__device__ __forceinline__ int ld_dst(const int* ei, int e, int f64) {
    return clampN(f64 ? ei[2 * NE + 2 * e] : ei[NE + e]);
}

// flags[0] = edge_index-is-int64, flags[1] = floats-are-bf16
__global__ void detect_flags(const int* __restrict__ ei, const void* __restrict__ hptr,
                             int* __restrict__ flags) {
    if (threadIdx.x != 0) return;
    flags[0] = (ei[1] == 0 && ei[3] == 0 && ei[5] == 0 && ei[7] == 0) ? 1 : 0;
    const ushort_t* hu = (const ushort_t*)hptr;
    int bf = 1;
    for (int i = 0; i < 512; i += 2) {
        uint_t ex = (hu[i] >> 7) & 0xFFu;
        if (ex > 0x8Cu) bf = 0;  // |v| >= ~1e4 -> not bf16 data
    }
    flags[1] = bf;
}

// M[l][h][d] = sum_c lin_edge_W[l, h*64+c, d] * att_edge[l, h, c]
__global__ void precompute_M(const void* __restrict__ lin_edge_W,
                             const void* __restrict__ att_edge,
                             float* __restrict__ Mbuf, const int* __restrict__ flags) {
    int isbf = flags[1];
    int tid = threadIdx.x;  // 512: l=tid>>8, h=(tid>>6)&3, c=tid&63
    int l = tid >> 8;
    int hc = tid & 255;
    float ae = ldx(att_edge, l * 256 + hc, isbf);
    size_t base = ((size_t)l * 256 + hc) * 3;
    float p0 = ae * ldx(lin_edge_W, base + 0, isbf);
    float p1 = ae * ldx(lin_edge_W, base + 1, isbf);
    float p2 = ae * ldx(lin_edge_W, base + 2, isbf);
    for (int off = 32; off > 0; off >>= 1) {
        p0 += __shfl_down(p0, off);
        p1 += __shfl_down(p1, off);
        p2 += __shfl_down(p2, off);
    }
    if ((tid & 63) == 0) {
        int h = (tid >> 6) & 3;
        Mbuf[(l * 4 + h) * 3 + 0] = p0;
        Mbuf[(l * 4 + h) * 3 + 1] = p1;
        Mbuf[(l * 4 + h) * 3 + 2] = p2;
    }
}

// W_ext[l][272][64] bf16: rows 0..255 = lin_W rows; 256..259 = u_src[h];
// 260..263 = u_dst[h]; 264..271 = 0.  u_src[h][d] = sum_c W[h*64+c][d]*att_src[h][c]
__global__ void precompute_W(const void* __restrict__ lin_W,
                             const void* __restrict__ att_src,
                             const void* __restrict__ att_dst,
                             ushort_t* __restrict__ wext,
                             const int* __restrict__ flags) {
    int isbf = flags[1];
    int idx = blockIdx.x * 256 + threadIdx.x;  // 2*272*64 = 34816
    if (idx >= 2 * 272 * 64) return;
    int d = idx & 63;
    int row = (idx >> 6) % 272;
    int l = idx / (272 * 64);
    float v = 0.f;
    if (row < 256) {
        v = ldx(lin_W, ((size_t)l * 256 + row) * 64 + d, isbf);
    } else if (row < 264) {
        int h = (row - 256) & 3;
        const void* att = (row < 260) ? att_src : att_dst;
        for (int c = 0; c < 64; ++c) {
            v += ldx(lin_W, ((size_t)l * 256 + h * 64 + c) * 64 + d, isbf) *
                 ldx(att, l * 256 + h * 64 + c, isbf);
        }
    }
    wext[((size_t)l * 272 + row) * 64 + d] = f2bf(v);
}

// ---------------- CSR build (once per launch; graph static across layers) ----

__global__ void csr_zero(int* __restrict__ deg) {
    int i = blockIdx.x * 256 + threadIdx.x;
    if (i < NN) deg[i] = 0;
}

// histogram + per-edge slot in one pass
__global__ void csr_hist_pos(const int* __restrict__ ei, int* __restrict__ deg,
                             int* __restrict__ pos, const int* __restrict__ flags) {
    int e = blockIdx.x * 256 + threadIdx.x;
    if (e >= NE) return;
    pos[e] = atomicAdd(&deg[ld_dst(ei, e, flags[0])], 1);
}

// block-level exclusive scan of deg -> rowptr; per-block totals -> bsum
__global__ __launch_bounds__(1024) void csr_scan1(const int* __restrict__ deg,
                                                  int* __restrict__ rowptr,
                                                  int* __restrict__ bsum) {
    __shared__ int sh[1024];
    int i = blockIdx.x * 1024 + threadIdx.x;
    int v = (i < NN) ? deg[i] : 0;
    sh[threadIdx.x] = v;
    __syncthreads();
    for (int off = 1; off < 1024; off <<= 1) {
        int t = (threadIdx.x >= off) ? sh[threadIdx.x - off] : 0;
        __syncthreads();
        sh[threadIdx.x] += t;
        __syncthreads();
    }
    if (i < NN) rowptr[i] = sh[threadIdx.x] - v;
    if (threadIdx.x == 1023) bsum[blockIdx.x] = sh[1023];
}

__global__ void csr_scan2(int* __restrict__ bsum, int nb) {
    if (threadIdx.x != 0) return;
    int run = 0;
    for (int b = 0; b < nb; ++b) {
        int t = bsum[b];
        bsum[b] = run;
        run += t;
    }
}

__global__ __launch_bounds__(1024) void csr_scan3(int* __restrict__ rowptr,
                                                  const int* __restrict__ bsum) {
    int i = blockIdx.x * 1024 + threadIdx.x;
    if (i < NN) rowptr[i] += bsum[blockIdx.x];
    if (i == 0) rowptr[NN] = NE;
}

// edata[slot] = {ea0, ea1, ea2, src-as-bits}, slot grouped by dst
__global__ void csr_fill(const int* __restrict__ ei, const void* __restrict__ edge_attr,
                         const int* __restrict__ rowptr, const int* __restrict__ pos,
                         float4* __restrict__ edata, const int* __restrict__ flags) {
    int e = blockIdx.x * 256 + threadIdx.x;
    if (e >= NE) return;
    int f64 = flags[0], isbf = flags[1];
    int s = ld_src(ei, e, f64), d = ld_dst(ei, e, f64);
    float4 ed;
    ed.x = ldx(edge_attr, (size_t)e * 3 + 0, isbf);
    ed.y = ldx(edge_attr, (size_t)e * 3 + 1, isbf);
    ed.z = ldx(edge_attr, (size_t)e * 3 + 2, isbf);
    ed.w = __int_as_float(s);
    edata[rowptr[d] + pos[e]] = ed;
}

// ---------------- per-layer kernels ----------------------------------------

// bf16 path: MFMA GEMM with operands SWAPPED (a=wext row, b=z row) so each
// lane owns ONE node (col=lane&15) and 4 consecutive wcols per tile (row=
// q*4+r). Packs 4 bf16 -> ds_write_b64 into a per-wave LDS tile, then a
// coalesced transform copy (4x ds_read_u16 + 8B global store per lane).
// Cols 256..263 of the extended GEMM give a_src/a_dst directly.
__global__ __launch_bounds__(256) void node_linear(
    const void* __restrict__ h_in,   // layer 0 input
    const void* __restrict__ zprev,  // layer>0 input (bf16 if isbf else f32)
    const void* __restrict__ lin_W,
    const void* __restrict__ att_src, const void* __restrict__ att_dst,
    const ushort_t* __restrict__ wext,  // L*272*64 bf16
    ushort_t* __restrict__ xb,          // N*256 bf16, [n][c*4+h]
    float* __restrict__ a_src, float* __restrict__ a_dst,
    const int* __restrict__ flags, int layer) {
    __shared__ __align__(16) char smem[4 * 16 * SROW * 2];  // 33792 B
    int isbf = flags[1];
    int tid = threadIdx.x;
    if (isbf) {
        int wave = tid >> 6, lane = tid & 63;
        int q = lane >> 4, mi = lane & 15;
        int mbase = blockIdx.x * MTILE + wave * 16;
        int mynode = mbase + mi;
        int mld = mynode < NN ? mynode : NN - 1;
        const ushort_t* zrow = (layer == 0)
            ? (const ushort_t*)h_in + (size_t)mld * 64
            : (const ushort_t*)zprev + (size_t)mld * 64;
        // B-fragment: this lane's node, 8 k's at q*8 (+32 for second tile)
        bf16x8 b0 = *(const bf16x8*)(zrow + q * 8);
        bf16x8 b1 = *(const bf16x8*)(zrow + 32 + q * 8);
        const ushort_t* wl = wext + (size_t)layer * 272 * 64;
        ushort_t* st = (ushort_t*)smem + wave * 16 * SROW;
        for (int t = 0; t < 17; ++t) {
            const ushort_t* wrow = wl + (size_t)(t * 16 + mi) * 64;
            bf16x8 a0 = *(const bf16x8*)(wrow + q * 8);
            bf16x8 a1 = *(const bf16x8*)(wrow + 32 + q * 8);
            f32x4 acc = {0.f, 0.f, 0.f, 0.f};
            // D[i][j] = sum_k A_i[k]*B_j[k]; C col=lane&15 -> node, row=q*4+r -> wcol
            acc = __builtin_amdgcn_mfma_f32_16x16x32_bf16(a0, b0, acc, 0, 0, 0);
            acc = __builtin_amdgcn_mfma_f32_16x16x32_bf16(a1, b1, acc, 0, 0, 0);
            if (t < 16) {
                ushort4 pk;
                pk.x = f2bf(acc[0]);
                pk.y = f2bf(acc[1]);
                pk.z = f2bf(acc[2]);
                pk.w = f2bf(acc[3]);
                // natural layout in LDS: [node_local][wcol], wcol = t*16+q*4+r
                *(ushort4*)(st + mi * SROW + t * 16 + q * 4) = pk;
            } else if (mynode < NN) {
                int j = q * 4;  // wcol-256 for r=0
#pragma unroll
                for (int r = 0; r < 4; ++r) {
                    int jj = j + r;
                    if (jj < 4) a_src[mynode * 4 + jj] = acc[r];
                    else if (jj < 8) a_dst[mynode * 4 + (jj - 4)] = acc[r];
                }
            }
        }
        // transform copy: [node][h*64+c] (LDS) -> xb[node][c*4+h] (global), coalesced
        for (int nn = 0; nn < 16; ++nn) {
            int node = mbase + nn;
            if (node >= NN) break;
            ushort4 pk;
            pk.x = st[nn * SROW + lane];
            pk.y = st[nn * SROW + 64 + lane];
            pk.z = st[nn * SROW + 128 + lane];
            pk.w = st[nn * SROW + 192 + lane];
            *(ushort4*)(xb + (size_t)node * 256 + lane * 4) = pk;
        }
        return;
    }
    // ---- f32 fallback (legacy path) ----
    float* zsh = (float*)smem;  // 64*64 f32 = 16384 B
    int base = blockIdx.x * MTILE;
    int nnodes = NN - base < MTILE ? NN - base : MTILE;
    for (int i = tid; i < nnodes * 64; i += 256) {
        zsh[i] = (layer == 0) ? ((const float*)h_in)[(size_t)base * 64 + i]
                              : ((const float*)zprev)[(size_t)base * 64 + i];
    }
    float w[64];
    size_t wrow = ((size_t)layer * 256 + tid) * 64;
    const float* wr = (const float*)lin_W + wrow;
#pragma unroll
    for (int i = 0; i < 64; ++i) w[i] = wr[i];
    float ats = ((const float*)att_src)[layer * 256 + tid];
    float atd = ((const float*)att_dst)[layer * 256 + tid];
    __syncthreads();
    int head = tid >> 6;
    int lane = tid & 63;
    for (int nn = 0; nn < nnodes; ++nn) {
        const float4* zr = (const float4*)&zsh[nn * 64];
        float acc = 0.f;
#pragma unroll
        for (int kk = 0; kk < 16; ++kk) {
            float4 zv = zr[kk];
            acc += zv.x * w[4 * kk] + zv.y * w[4 * kk + 1] +
                   zv.z * w[4 * kk + 2] + zv.w * w[4 * kk + 3];
        }
        int n = base + nn;
        xb[(size_t)n * 256 + lane * 4 + head] = f2bf(acc);
        float ps = acc * ats, pd = acc * atd;
        for (int off = 32; off > 0; off >>= 1) {
            ps += __shfl_down(ps, off);
            pd += __shfl_down(pd, off);
        }
        if (lane == 0) {
            a_src[n * 4 + head] = ps;
            a_dst[n * 4 + head] = pd;
        }
    }
}

// One wave per node: softmax-weighted neighbor aggregation (no atomics),
// head-mean + bias, LayerNorm, SiLU. z written bf16 (isbf) or f32.
__global__ __launch_bounds__(256) void node_aggregate(
    const int* __restrict__ rowptr, const float4* __restrict__ edata,
    const float* __restrict__ a_src, const float* __restrict__ a_dst,
    const ushort_t* __restrict__ xb, const float* __restrict__ Mbuf,
    const void* __restrict__ bias, const void* __restrict__ gamma,
    const void* __restrict__ beta, void* __restrict__ zout,
    void* __restrict__ outp, const int* __restrict__ flags, int layer, int last) {
    int isbf = flags[1];
    int n = blockIdx.x * 4 + (threadIdx.x >> 6);
    int lane = threadIdx.x & 63;
    float M[12];
#pragma unroll
    for (int i = 0; i < 12; ++i) M[i] = Mbuf[layer * 12 + i];
    float4 ad = *(const float4*)(a_dst + (size_t)n * 4);
    int start = rowptr[n], end = rowptr[n + 1];
    float acc0 = 0.f, acc1 = 0.f, acc2 = 0.f, acc3 = 0.f;
    float den0 = 0.f, den1 = 0.f, den2 = 0.f, den3 = 0.f;
    for (int cb = start; cb < end; cb += 64) {
        int m = end - cb;
        if (m > 64) m = 64;
        float ex0 = 0.f, ex1 = 0.f, ex2 = 0.f, ex3 = 0.f;
        int s = 0;
        if (lane < m) {
            float4 ed = edata[cb + lane];
            s = __float_as_int(ed.w);
            float4 as4 = *(const float4*)(a_src + (size_t)s * 4);
            float t0 = as4.x + ad.x + ed.x * M[0] + ed.y * M[1] + ed.z * M[2];
            float t1 = as4.y + ad.y + ed.x * M[3] + ed.y * M[4] + ed.z * M[5];
            float t2 = as4.z + ad.z + ed.x * M[6] + ed.y * M[7] + ed.z * M[8];
            float t3 = as4.w + ad.w + ed.x * M[9] + ed.y * M[10] + ed.z * M[11];
            t0 = t0 > 0.f ? t0 : NEG_SLOPE * t0;
            t1 = t1 > 0.f ? t1 : NEG_SLOPE * t1;
            t2 = t2 > 0.f ? t2 : NEG_SLOPE * t2;
            t3 = t3 > 0.f ? t3 : NEG_SLOPE * t3;
            ex0 = __expf(fminf(t0, 80.f));
            ex1 = __expf(fminf(t1, 80.f));
            ex2 = __expf(fminf(t2, 80.f));
            ex3 = __expf(fminf(t3, 80.f));
            den0 += ex0; den1 += ex1; den2 += ex2; den3 += ex3;
        }
        for (int j = 0; j < m; ++j) {
            int sj = __shfl(s, j);
            float w0 = __shfl(ex0, j), w1 = __shfl(ex1, j);
            float w2 = __shfl(ex2, j), w3 = __shfl(ex3, j);
            ushort4 xv = *(const ushort4*)(xb + (size_t)sj * 256 + lane * 4);
            acc0 += w0 * bf2f(xv.x);
            acc1 += w1 * bf2f(xv.y);
            acc2 += w2 * bf2f(xv.z);
            acc3 += w3 * bf2f(xv.w);
        }
    }
    for (int off = 1; off < 64; off <<= 1) {
        den0 += __shfl_xor(den0, off);
        den1 += __shfl_xor(den1, off);
        den2 += __shfl_xor(den2, off);
        den3 += __shfl_xor(den3, off);
    }
    float v = ldx(bias, layer * 64 + lane, isbf) +
              0.25f * (acc0 / (den0 + 1e-16f) + acc1 / (den1 + 1e-16f) +
                       acc2 / (den2 + 1e-16f) + acc3 / (den3 + 1e-16f));
    float sum = v;
    for (int off = 1; off < 64; off <<= 1) sum += __shfl_xor(sum, off);
    float mu = sum * (1.f / 64.f);
    float d = v - mu;
    float vv = d * d;
    for (int off = 1; off < 64; off <<= 1) vv += __shfl_xor(vv, off);
    float var = vv * (1.f / 64.f);
    float ln = d * rsqrtf(var + LN_EPS) * ldx(gamma, layer * 64 + lane, isbf) +
               ldx(beta, layer * 64 + lane, isbf);
    float sl = ln / (1.f + __expf(-ln));
    size_t idx = (size_t)n * 64 + lane;
    if (last) {
        if (isbf) ((ushort_t*)outp)[idx] = f2bf(sl);
        else      ((float*)outp)[idx] = sl;
    } else {
        if (isbf) ((ushort_t*)zout)[idx] = f2bf(sl);
        else      ((float*)zout)[idx] = sl;
    }
}

extern "C" void kernel_launch(void* const* d_in, const int* in_sizes, int n_in,
                              void* d_out, int out_size, void* d_ws, size_t ws_size,
                              hipStream_t stream) {
    int off = (in_sizes[0] == 1) ? 1 : 0;
    const void* h_in  = d_in[off + 0];
    const int*  ei    = (const int*)d_in[off + 1];
    const void* eattr = d_in[off + 2];
    const void* linW  = d_in[off + 3];
    const void* linEW = d_in[off + 4];
    const void* attS  = d_in[off + 5];
    const void* attD  = d_in[off + 6];
    const void* attE  = d_in[off + 7];
    const void* bias  = d_in[off + 8];
    const void* gamma = d_in[off + 9];
    const void* beta  = d_in[off + 10];

    // bump allocator, 256 B aligned (~56.5 MB total)
    char* w = (char*)d_ws;
    size_t o = 0;
    auto alloc = [&](size_t bytes) {
        void* p = w + o;
        o += (bytes + 255) & ~(size_t)255;
        return p;
    };
    int*    flags  = (int*)alloc(8);
    float*  Mbuf   = (float*)alloc(24 * 4);
    ushort_t* wext = (ushort_t*)alloc((size_t)2 * 272 * 64 * 2);
    float*  a_src  = (float*)alloc((size_t)NN * 4 * 4);
    float*  a_dst  = (float*)alloc((size_t)NN * 4 * 4);
    int*    rowptr = (int*)alloc((size_t)(NN + 1) * 4);
    int*    deg    = (int*)alloc((size_t)NN * 4);
    int*    pos    = (int*)alloc((size_t)NE * 4);
    int*    bsum   = (int*)alloc(64 * 4);
    void*   zbuf   = alloc((size_t)NN * 64 * 4);  // f32-sized; bf16 when isbf
    ushort_t* xb   = (ushort_t*)alloc((size_t)NN * 256 * 2);
    float4* edata  = (float4*)alloc((size_t)NE * 16);

    detect_flags<<<1, 64, 0, stream>>>(ei, h_in, flags);
    precompute_M<<<1, 512, 0, stream>>>(linEW, attE, Mbuf, flags);
    precompute_W<<<136, 256, 0, stream>>>(linW, attS, attD, wext, flags);
    int nb = (NN + 1023) / 1024;  // 49
    csr_zero<<<(NN + 255) / 256, 256, 0, stream>>>(deg);
    csr_hist_pos<<<(NE + 255) / 256, 256, 0, stream>>>(ei, deg, pos, flags);
    csr_scan1<<<nb, 1024, 0, stream>>>(deg, rowptr, bsum);
    csr_scan2<<<1, 64, 0, stream>>>(bsum, nb);
    csr_scan3<<<nb, 1024, 0, stream>>>(rowptr, bsum);
    csr_fill<<<(NE + 255) / 256, 256, 0, stream>>>(ei, eattr, rowptr, pos, edata, flags);

    int nlb = (NN + MTILE - 1) / MTILE;  // 782
    for (int l = 0; l < 2; ++l) {
        node_linear<<<nlb, 256, 0, stream>>>(h_in, zbuf, linW, attS, attD, wext,
                                             xb, a_src, a_dst, flags, l);
        node_aggregate<<<NN / 4, 256, 0, stream>>>(rowptr, edata, a_src, a_dst,
                                                   xb, Mbuf, bias, gamma, beta,
                                                   zbuf, d_out, flags, l, l == 1);
    }
}